// Round 1
// baseline (762.144 us; speedup 1.0000x reference)
//
#include <hip/hip_runtime.h>
#include <stdint.h>

#define DIN 4096
#define DOUT 4096
#define RNK 8
#define MROWS 8192   // B*S = 4*2048

typedef unsigned short u16;
typedef __attribute__((ext_vector_type(8))) short short8;
typedef __attribute__((ext_vector_type(8))) unsigned short u16x8;
typedef __attribute__((ext_vector_type(4))) float f32x4;

// ---------- helpers ----------
__device__ __forceinline__ u16 f2bf(float f) {
    union { float f; uint32_t u; } v; v.f = f;
    uint32_t u = v.u;
    uint32_t r = (u + 0x7fffu + ((u >> 16) & 1u)) >> 16;   // RNE
    return (u16)r;
}

__device__ __forceinline__ void gl_lds16(const u16* g, u16* lds) {
    // direct global->LDS DMA, 16B per lane; LDS dest = wave-uniform base + lane*16
    __builtin_amdgcn_global_load_lds((const __attribute__((address_space(1))) unsigned int*)g,
                                     (__attribute__((address_space(3))) unsigned int*)lds,
                                     16, 0, 0);
}

// ---------- K1: normalize columns of hra_u -> Un[i][d] (column-major by i) ----------
__global__ __launch_bounds__(256) void k_normalize_u(const float* __restrict__ hra_u,
                                                     float* __restrict__ Un) {
    const int i = blockIdx.x;        // column 0..7
    const int t = threadIdx.x;
    float ss = 0.f;
    for (int d = t; d < DIN; d += 256) {
        float v = hra_u[d * RNK + i];
        ss += v * v;
    }
    for (int off = 32; off; off >>= 1) ss += __shfl_down(ss, off, 64);
    __shared__ float red[4];
    if ((t & 63) == 0) red[t >> 6] = ss;
    __syncthreads();
    float inv = rsqrtf(red[0] + red[1] + red[2] + red[3]);
    for (int d = t; d < DIN; d += 256)
        Un[i * DIN + d] = hra_u[d * RNK + i] * inv;
}

// ---------- K2: Gram matrix G[i][j] = Un[i] . Un[j] ----------
__global__ __launch_bounds__(256) void k_gram(const float* __restrict__ Un,
                                              float* __restrict__ G) {
    const int t = threadIdx.x;
    float acc[RNK][RNK] = {};
    for (int d = t; d < DIN; d += 256) {
        float u[RNK];
        #pragma unroll
        for (int i = 0; i < RNK; i++) u[i] = Un[i * DIN + d];
        #pragma unroll
        for (int i = 0; i < RNK; i++)
            #pragma unroll
            for (int j = 0; j < RNK; j++)
                acc[i][j] += u[i] * u[j];
    }
    #pragma unroll
    for (int i = 0; i < RNK; i++)
        #pragma unroll
        for (int j = 0; j < RNK; j++)
            for (int off = 32; off; off >>= 1)
                acc[i][j] += __shfl_down(acc[i][j], off, 64);
    __shared__ float red[4][64];
    if ((t & 63) == 0) {
        #pragma unroll
        for (int i = 0; i < RNK; i++)
            #pragma unroll
            for (int j = 0; j < RNK; j++)
                red[t >> 6][i * RNK + j] = acc[i][j];
    }
    __syncthreads();
    if (t < 64) G[t] = red[0][t] + red[1][t] + red[2][t] + red[3][t];
}

// ---------- K3: per row o: v = W[o,:] @ Un^T, then y_i = 2(v_i - sum_{j<i} y_j G[j,i]) ----------
__global__ __launch_bounds__(256) void k_wy(const float* __restrict__ W,
                                            const float* __restrict__ Un,
                                            const float* __restrict__ G,
                                            float* __restrict__ Y) {
    const int o = blockIdx.x;
    const int t = threadIdx.x;
    const float* wrow = W + (size_t)o * DIN;
    float acc[RNK] = {};
    for (int d = t; d < DIN; d += 256) {
        float wv = wrow[d];
        #pragma unroll
        for (int i = 0; i < RNK; i++) acc[i] += wv * Un[i * DIN + d];
    }
    #pragma unroll
    for (int i = 0; i < RNK; i++)
        for (int off = 32; off; off >>= 1)
            acc[i] += __shfl_down(acc[i], off, 64);
    __shared__ float red[4][RNK];
    if ((t & 63) == 0) {
        #pragma unroll
        for (int i = 0; i < RNK; i++) red[t >> 6][i] = acc[i];
    }
    __syncthreads();
    if (t == 0) {
        float y[RNK];
        #pragma unroll
        for (int i = 0; i < RNK; i++) {
            float s = red[0][i] + red[1][i] + red[2][i] + red[3][i];
            for (int j = 0; j < i; j++) s -= y[j] * G[j * RNK + i];
            y[i] = 2.f * s;
            Y[(size_t)o * RNK + i] = y[i];
        }
    }
}

// ---------- K4: W'[o][d] = W[o][d] - sum_i Y[o][i]*Un[i][d], cast to bf16 ----------
__global__ __launch_bounds__(256) void k_build_w(const float* __restrict__ W,
                                                 const float* __restrict__ Un,
                                                 const float* __restrict__ Y,
                                                 u16* __restrict__ Wb) {
    const int c = blockIdx.x * 256 + threadIdx.x;  // float4 chunk id
    const int o = c >> 10;                         // row (1024 chunks per row)
    const int d = (c & 1023) * 4;
    float y[RNK];
    #pragma unroll
    for (int i = 0; i < RNK; i++) y[i] = Y[(size_t)o * RNK + i];
    float4 r = *(const float4*)(W + (size_t)o * DIN + d);
    #pragma unroll
    for (int i = 0; i < RNK; i++) {
        float4 uv = *(const float4*)(Un + i * DIN + d);
        r.x -= y[i] * uv.x; r.y -= y[i] * uv.y;
        r.z -= y[i] * uv.z; r.w -= y[i] * uv.w;
    }
    ushort4 ov;
    ov.x = f2bf(r.x); ov.y = f2bf(r.y); ov.z = f2bf(r.z); ov.w = f2bf(r.w);
    *(ushort4*)(Wb + (size_t)o * DIN + d) = ov;
}

// ---------- K5: cast x (fp32) -> bf16 ----------
__global__ __launch_bounds__(256) void k_cast_x(const float* __restrict__ x,
                                                u16* __restrict__ xb) {
    const size_t idx = (size_t)blockIdx.x * 256 + threadIdx.x;  // 8 elems each
    float4 a = *(const float4*)(x + idx * 8);
    float4 b = *(const float4*)(x + idx * 8 + 4);
    u16x8 o;
    o[0] = f2bf(a.x); o[1] = f2bf(a.y); o[2] = f2bf(a.z); o[3] = f2bf(a.w);
    o[4] = f2bf(b.x); o[5] = f2bf(b.y); o[6] = f2bf(b.z); o[7] = f2bf(b.w);
    *(u16x8*)(xb + idx * 8) = o;
}

// ---------- K6: main GEMM  C[M,N] = A[M,K] @ B[N,K]^T + bias ----------
// 128x128 tile, BK=32, 256 threads = 4 waves (2x2), each wave 64x64 via 4x4 MFMA 16x16x32
__global__ __launch_bounds__(256) void k_gemm(const u16* __restrict__ A,   // x bf16 [M][K]
                                              const u16* __restrict__ B,   // W' bf16 [N][K]
                                              const float* __restrict__ bias,
                                              float* __restrict__ C) {
    __shared__ u16 As[128 * 32];   // 8 KiB, row-major [m][k]
    __shared__ u16 Bs[128 * 32];

    const int t = threadIdx.x;
    const int w = t >> 6, l = t & 63;
    const int bm = blockIdx.x & 63;   // M/128 = 64
    const int bn = blockIdx.x >> 6;   // N/128 = 32
    const int wm = w & 1, wn = w >> 1;

    // staging: wave w covers 32 rows (w*32..w*32+31); lane l -> row (l>>2), 16B chunk (l&3)
    const int srow = w * 32 + (l >> 2);
    const int kcol = (l & 3) * 8;
    const u16* agp = A + (size_t)(bm * 128 + srow) * DIN + kcol;
    const u16* bgp = B + (size_t)(bn * 128 + srow) * DIN + kcol;
    u16* asw = &As[w * 1024];   // wave-uniform LDS bases (bytes: w*2048)
    u16* bsw = &Bs[w * 1024];

    const int quad = l >> 4, lane16 = l & 15;

    f32x4 acc[4][4] = {};

    for (int k0 = 0; k0 < DIN; k0 += 32) {
        __syncthreads();   // previous compute done before overwrite
        gl_lds16(agp + k0,            asw);
        gl_lds16(agp + k0 + 16 * DIN, asw + 512);
        gl_lds16(bgp + k0,            bsw);
        gl_lds16(bgp + k0 + 16 * DIN, bsw + 512);
        __syncthreads();   // compiler emits vmcnt(0) drain before barrier

        short8 a_frag[4], b_frag[4];
        #pragma unroll
        for (int mt = 0; mt < 4; mt++)
            a_frag[mt] = *(const short8*)&As[(wm * 64 + mt * 16 + lane16) * 32 + quad * 8];
        #pragma unroll
        for (int nt = 0; nt < 4; nt++)
            b_frag[nt] = *(const short8*)&Bs[(wn * 64 + nt * 16 + lane16) * 32 + quad * 8];
        #pragma unroll
        for (int mt = 0; mt < 4; mt++)
            #pragma unroll
            for (int nt = 0; nt < 4; nt++)
                acc[mt][nt] = __builtin_amdgcn_mfma_f32_16x16x32_bf16(
                    a_frag[mt], b_frag[nt], acc[mt][nt], 0, 0, 0);
    }

    // epilogue: D layout col=lane&15, row=quad*4+reg
    const int col0 = bn * 128 + wn * 64 + lane16;
    const int row0 = bm * 128 + wm * 64 + quad * 4;
    #pragma unroll
    for (int nt = 0; nt < 4; nt++) {
        float bv = bias[col0 + nt * 16];
        #pragma unroll
        for (int mt = 0; mt < 4; mt++) {
            #pragma unroll
            for (int rr = 0; rr < 4; rr++) {
                C[(size_t)(row0 + mt * 16 + rr) * DOUT + col0 + nt * 16] =
                    acc[mt][nt][rr] + bv;
            }
        }
    }
}

extern "C" void kernel_launch(void* const* d_in, const int* in_sizes, int n_in,
                              void* d_out, int out_size, void* d_ws, size_t ws_size,
                              hipStream_t stream) {
    const float* x     = (const float*)d_in[0];   // [4,2048,4096]
    const float* hra_u = (const float*)d_in[1];   // [4096,8]
    const float* W     = (const float*)d_in[2];   // [4096,4096]
    const float* bias  = (const float*)d_in[3];   // [4096]
    float* out = (float*)d_out;

    char* ws = (char*)d_ws;
    float* Un = (float*)(ws);                         // 8*4096*4   = 131072 B
    float* G  = (float*)(ws + 131072);                // 64*4       = 256 B
    float* Y  = (float*)(ws + 131072 + 512);          // 4096*8*4   = 131072 B
    u16*   Wb = (u16*)(ws + 524288);                  // 4096*4096*2 = 33554432 B
    u16*   xb = (u16*)(ws + 524288 + 33554432);       // 8192*4096*2 = 67108864 B

    k_normalize_u<<<RNK, 256, 0, stream>>>(hra_u, Un);
    k_gram<<<1, 256, 0, stream>>>(Un, G);
    k_wy<<<DOUT, 256, 0, stream>>>(W, Un, G, Y);
    k_build_w<<<(DOUT * DIN / 4) / 256, 256, 0, stream>>>(W, Un, Y, Wb);
    k_cast_x<<<(MROWS * DIN / 8) / 256, 256, 0, stream>>>(x, xb);
    k_gemm<<<(MROWS / 128) * (DIN /* N */ / 128), 256, 0, stream>>>(xb, Wb, bias, out);
}